// Round 6
// baseline (108.929 us; speedup 1.0000x reference)
//
#include <hip/hip_runtime.h>
#include <math.h>

#define EPS 1e-5f

constexpr int Bc = 16, Cc = 32, Dc = 32, Hc = 64, Wc = 64;
constexpr int Pc = 8, HIDc = 256, OUTc = 128;
constexpr int NBINS = Bc * Cc * Pc;                 // 4096 pooling bins
constexpr float NPC_INV = 1.0f / (float)(Bc * Dc * Hc * Wc);  // 1 / 2097152

typedef float fx4 __attribute__((ext_vector_type(4)));  // NT-loadable 16B vector

// ws layout (floats): [0,4096) max | [4096,8192) min | [8192,12288) sum | [12288,16384) sumsq

// ---------------- Kernel 1: one pass over x, per-bin max/min/sum/sumsq ----------------
// ATTRIBUTION ROUND: launched TWICE (idempotent) so Delta(total) vs round 5 = k1 duration.
// Body byte-identical to round 5.
__global__ __launch_bounds__(256) void k1_stats(const float* __restrict__ x,
                                                float* __restrict__ ws,
                                                const float* __restrict__ w_ih,
                                                const float* __restrict__ w_hh,
                                                const float* __restrict__ w_out) {
    const int bid = blockIdx.x;
    const int t = threadIdx.x;

    // ---- L2 weight warming (kept live via empty asm; rule #17) ----
    {
        const int slice = bid & 31;
        const float4* wh4 = reinterpret_cast<const float4*>(w_hh) + slice * 512 + t;
        float4 v0 = wh4[0];
        float4 v1 = wh4[256];
        const float4* wo4 = reinterpret_cast<const float4*>(w_out) + slice * 256 + t;
        float4 v2 = wo4[0];
        float d = v0.x + v1.x + v2.x;
        if (t < 64) {
            const float4* wi4 = reinterpret_cast<const float4*>(w_ih) + slice * 64 + t;
            float4 v3 = wi4[0];
            d += v3.x;
        }
        asm volatile("" :: "v"(d));
    }

    const fx4* px = reinterpret_cast<const fx4*>(x) + ((size_t)bid << 12); // 4096 fx4/bin

    float vmax = -INFINITY, vmin = INFINITY, s = 0.f, ss = 0.f;
#pragma unroll
    for (int j = 0; j < 16; ++j) {
        fx4 v = __builtin_nontemporal_load(&px[j * 256 + t]);
        vmax = fmaxf(vmax, fmaxf(fmaxf(v.x, v.y), fmaxf(v.z, v.w)));
        vmin = fminf(vmin, fminf(fminf(v.x, v.y), fminf(v.z, v.w)));
        s += (v.x + v.y) + (v.z + v.w);
        ss = fmaf(v.x, v.x, ss); ss = fmaf(v.y, v.y, ss);
        ss = fmaf(v.z, v.z, ss); ss = fmaf(v.w, v.w, ss);
    }
    // wave (64-lane) butterfly reduce
#pragma unroll
    for (int off = 1; off < 64; off <<= 1) {
        vmax = fmaxf(vmax, __shfl_xor(vmax, off));
        vmin = fminf(vmin, __shfl_xor(vmin, off));
        s += __shfl_xor(s, off);
        ss += __shfl_xor(ss, off);
    }
    __shared__ float r[4][4];
    const int wid = t >> 6;
    if ((t & 63) == 0) { r[wid][0] = vmax; r[wid][1] = vmin; r[wid][2] = s; r[wid][3] = ss; }
    __syncthreads();
    if (t == 0) {
        vmax = fmaxf(fmaxf(r[0][0], r[1][0]), fmaxf(r[2][0], r[3][0]));
        vmin = fminf(fminf(r[0][1], r[1][1]), fminf(r[2][1], r[3][1]));
        s  = (r[0][2] + r[1][2]) + (r[2][2] + r[3][2]);
        ss = (r[0][3] + r[1][3]) + (r[2][3] + r[3][3]);
        ws[bid]             = vmax;
        ws[NBINS + bid]     = vmin;
        ws[2 * NBINS + bid] = s;
        ws[3 * NBINS + bid] = ss;
    }
}

// ---------------- Kernel 2: byte-identical to round 5 ----------------
__global__ __launch_bounds__(1024) void k2_rnn(const float* __restrict__ ws,
                                               const float* __restrict__ bn_gamma,
                                               const float* __restrict__ bn_beta,
                                               const float* __restrict__ w_ih,
                                               const float* __restrict__ b_ih,
                                               const float* __restrict__ w_hh,
                                               const float* __restrict__ b_hh,
                                               const float* __restrict__ w_out,
                                               const float* __restrict__ b_out,
                                               const float* __restrict__ ln_gamma,
                                               const float* __restrict__ ln_beta,
                                               float* __restrict__ out) {
    const int b = blockIdx.x;
    const int t = threadIdx.x;
    const int h = t & 255;
    const int q = t >> 8;

    __shared__ float scale_s[Cc], shift_s[Cc];
    __shared__ __align__(16) float pooled[Pc][Cc];
    __shared__ __align__(16) float u[Pc][HIDc];
    __shared__ __align__(16) float hx[HIDc];
    __shared__ __align__(16) float part[4][HIDc];
    __shared__ __align__(16) float o[OUTc];
    __shared__ float red2[2];

    // ---- Stage A: channel stats (redundant per block; ws is L2-hot) ----
    {
        const int c = t >> 5, r = t & 31;   // 32 threads per channel
        float s = 0.f, ss = 0.f;
#pragma unroll
        for (int j = 0; j < 4; ++j) {
            const int i = r + 32 * j;       // i in [0,128): i = b'*8 + p
            const int bid = ((i >> 3) * Cc + c) * Pc + (i & 7);
            s  += ws[2 * NBINS + bid];
            ss += ws[3 * NBINS + bid];
        }
#pragma unroll
        for (int off = 1; off < 32; off <<= 1) {
            s  += __shfl_xor(s, off);
            ss += __shfl_xor(ss, off);
        }
        if (r == 0) {
            const float mean = s * NPC_INV;
            const float var  = ss * NPC_INV - mean * mean;
            const float sc   = bn_gamma[c] * rsqrtf(var + EPS);
            scale_s[c] = sc;
            shift_s[c] = bn_beta[c] - mean * sc;
        }
    }
    __syncthreads();

    // ---- Stage B: pooled[p][c] = relu(scale * (scale>=0 ? max : min) + shift) ----
    if (t < Pc * Cc) {
        const int p = t >> 5, c = t & 31;
        const int bid = (b * Cc + c) * Pc + p;
        const float sc = scale_s[c];
        const float xm = (sc >= 0.f) ? ws[bid] : ws[NBINS + bid];
        pooled[p][c] = fmaxf(fmaf(sc, xm, shift_s[c]), 0.f);
    }
    __syncthreads();

    // ---- Issue w_hh segment loads, then stage C covers the latency ----
    float4 wreg[16];
    {
        const float4* wr = reinterpret_cast<const float4*>(w_hh) + h * (HIDc / 4) + q * 16;
#pragma unroll
        for (int e = 0; e < 16; ++e) wreg[e] = wr[e];
    }

    // ---- Stage C: u[p][h] for p = q and p = q+4 ----
    {
        const float4* wi = reinterpret_cast<const float4*>(w_ih) + h * (Cc / 4);
        float4 wiv[8];
#pragma unroll
        for (int e = 0; e < 8; ++e) wiv[e] = wi[e];
        const float bias = b_ih[h] + b_hh[h];
#pragma unroll
        for (int pp = 0; pp < 2; ++pp) {
            const int p = q + 4 * pp;
            const float4* pl = reinterpret_cast<const float4*>(&pooled[p][0]);
            float a0 = bias, a1 = 0.f, a2 = 0.f, a3 = 0.f;
#pragma unroll
            for (int e = 0; e < 8; ++e) {
                float4 pv = pl[e];
                a0 = fmaf(pv.x, wiv[e].x, a0);
                a1 = fmaf(pv.y, wiv[e].y, a1);
                a2 = fmaf(pv.z, wiv[e].z, a2);
                a3 = fmaf(pv.w, wiv[e].w, a3);
            }
            u[p][h] = (a0 + a1) + (a2 + a3);
        }
    }
    __syncthreads();

    // step 0: hx = relu(u[0])  (hx_prev = 0)
    if (t < HIDc) hx[t] = fmaxf(u[0][t], 0.f);
    __syncthreads();

    // ---- Stage D: 7 recurrent steps; serial chain is LDS + FMA only ----
    for (int step = 1; step < Pc; ++step) {
        const float4* hv4 = reinterpret_cast<const float4*>(&hx[q * 64]);
        float a0 = 0.f, a1 = 0.f, a2 = 0.f, a3 = 0.f;
#pragma unroll
        for (int e = 0; e < 16; ++e) {
            float4 wv = wreg[e];
            float4 hv = hv4[e];
            a0 = fmaf(hv.x, wv.x, a0);
            a1 = fmaf(hv.y, wv.y, a1);
            a2 = fmaf(hv.z, wv.z, a2);
            a3 = fmaf(hv.w, wv.w, a3);
        }
        part[q][h] = (a0 + a1) + (a2 + a3);
        __syncthreads();
        if (q == 0) {
            const float v = u[step][h] + ((part[0][h] + part[1][h]) + (part[2][h] + part[3][h]));
            hx[h] = fmaxf(v, 0.f);
        }
        __syncthreads();
    }

    // ---- Stage E: out = hx @ w_out^T + b_out (4 threads per output, shfl reduce) ----
    if (t < 4 * OUTc) {
        const int oi = t >> 2, seg = t & 3;
        const float4* wo = reinterpret_cast<const float4*>(w_out) + oi * (HIDc / 4) + seg * 16;
        const float4* hv4 = reinterpret_cast<const float4*>(&hx[seg * 64]);
        float a0 = (seg == 0) ? b_out[oi] : 0.f, a1 = 0.f, a2 = 0.f, a3 = 0.f;
#pragma unroll
        for (int e = 0; e < 16; ++e) {
            float4 wv = wo[e];
            float4 hv = hv4[e];
            a0 = fmaf(hv.x, wv.x, a0);
            a1 = fmaf(hv.y, wv.y, a1);
            a2 = fmaf(hv.z, wv.z, a2);
            a3 = fmaf(hv.w, wv.w, a3);
        }
        float s = (a0 + a1) + (a2 + a3);
        s += __shfl_xor(s, 1);
        s += __shfl_xor(s, 2);
        if (seg == 0) o[oi] = s;
    }
    __syncthreads();

    // ---- LayerNorm over 128 ----
    if (t < 64) {
        const float x0 = o[t], x1 = o[t + 64];
        float s = x0 + x1, ss = x0 * x0 + x1 * x1;
#pragma unroll
        for (int off = 1; off < 64; off <<= 1) {
            s  += __shfl_xor(s, off);
            ss += __shfl_xor(ss, off);
        }
        if (t == 0) { red2[0] = s; red2[1] = ss; }
    }
    __syncthreads();
    if (t < OUTc) {
        const float mu  = red2[0] * (1.0f / OUTc);
        const float var = red2[1] * (1.0f / OUTc) - mu * mu;
        const float rs  = rsqrtf(var + EPS);
        out[b * OUTc + t] = (o[t] - mu) * rs * ln_gamma[t] + ln_beta[t];
    }
}

extern "C" void kernel_launch(void* const* d_in, const int* in_sizes, int n_in,
                              void* d_out, int out_size, void* d_ws, size_t ws_size,
                              hipStream_t stream) {
    const float* x        = (const float*)d_in[0];
    const float* bn_gamma = (const float*)d_in[1];
    const float* bn_beta  = (const float*)d_in[2];
    const float* w_ih     = (const float*)d_in[3];
    const float* b_ih     = (const float*)d_in[4];
    const float* w_hh     = (const float*)d_in[5];
    const float* b_hh     = (const float*)d_in[6];
    const float* w_out    = (const float*)d_in[7];
    const float* b_out    = (const float*)d_in[8];
    const float* ln_gamma = (const float*)d_in[9];
    const float* ln_beta  = (const float*)d_in[10];
    float* out = (float*)d_out;
    float* ws  = (float*)d_ws;

    // ATTRIBUTION: k1 launched twice (idempotent). Delta vs round 5 total = k1 duration.
    k1_stats<<<NBINS, 256, 0, stream>>>(x, ws, w_ih, w_hh, w_out);
    k1_stats<<<NBINS, 256, 0, stream>>>(x, ws, w_ih, w_hh, w_out);
    k2_rnn<<<Bc, 1024, 0, stream>>>(ws, bn_gamma, bn_beta, w_ih, b_ih, w_hh, b_hh,
                                    w_out, b_out, ln_gamma, ln_beta, out);
}

// Round 7
// 70.401 us; speedup vs baseline: 1.5473x; 1.5473x over previous
//
#include <hip/hip_runtime.h>
#include <math.h>

#define EPS 1e-5f

constexpr int Bc = 16, Cc = 32, Dc = 32, Hc = 64, Wc = 64;
constexpr int Pc = 8, HIDc = 256, OUTc = 128;
constexpr int NBINS = Bc * Cc * Pc;                 // 4096 pooling bins
constexpr float NPC_INV = 1.0f / (float)(Bc * Dc * Hc * Wc);  // 1 / 2097152

typedef float fx4 __attribute__((ext_vector_type(4)));  // NT-loadable 16B vector

// ws layout (floats): [0,4096) max | [4096,8192) min | [8192,12288) sum | [12288,16384) sumsq

// ---------------- Kernel 1: one pass over x, per-bin max/min/sum/sumsq ----------------
// At the read ceiling (41 us = 6.5 TB/s, round-6 attribution). Weight-warm removed (r5: null).
__global__ __launch_bounds__(256) void k1_stats(const float* __restrict__ x,
                                                float* __restrict__ ws) {
    const int bid = blockIdx.x;
    const int t = threadIdx.x;
    const fx4* px = reinterpret_cast<const fx4*>(x) + ((size_t)bid << 12); // 4096 fx4/bin

    float vmax = -INFINITY, vmin = INFINITY, s = 0.f, ss = 0.f;
#pragma unroll
    for (int j = 0; j < 16; ++j) {
        fx4 v = __builtin_nontemporal_load(&px[j * 256 + t]);
        vmax = fmaxf(vmax, fmaxf(fmaxf(v.x, v.y), fmaxf(v.z, v.w)));
        vmin = fminf(vmin, fminf(fminf(v.x, v.y), fminf(v.z, v.w)));
        s += (v.x + v.y) + (v.z + v.w);
        ss = fmaf(v.x, v.x, ss); ss = fmaf(v.y, v.y, ss);
        ss = fmaf(v.z, v.z, ss); ss = fmaf(v.w, v.w, ss);
    }
#pragma unroll
    for (int off = 1; off < 64; off <<= 1) {
        vmax = fmaxf(vmax, __shfl_xor(vmax, off));
        vmin = fminf(vmin, __shfl_xor(vmin, off));
        s += __shfl_xor(s, off);
        ss += __shfl_xor(ss, off);
    }
    __shared__ float r[4][4];
    const int wid = t >> 6;
    if ((t & 63) == 0) { r[wid][0] = vmax; r[wid][1] = vmin; r[wid][2] = s; r[wid][3] = ss; }
    __syncthreads();
    if (t == 0) {
        vmax = fmaxf(fmaxf(r[0][0], r[1][0]), fmaxf(r[2][0], r[3][0]));
        vmin = fminf(fminf(r[0][1], r[1][1]), fminf(r[2][1], r[3][1]));
        s  = (r[0][2] + r[1][2]) + (r[2][2] + r[3][2]);
        ss = (r[0][3] + r[1][3]) + (r[2][3] + r[3][3]);
        ws[bid]             = vmax;
        ws[NBINS + bid]     = vmin;
        ws[2 * NBINS + bid] = s;
        ws[3 * NBINS + bid] = ss;
    }
}

// ---------------- Kernel 2: 16 blocks x 256 threads; thread h owns output h ----------------
// Full w_hh row in registers (64 x float4). Per RNN step: 64 broadcast ds_read_b128 of hx
// + 256 FMA + ONE 4-wave barrier (double-buffered hx). No split-K partials, no idle waves.
__global__ __launch_bounds__(256, 1) void k2_rnn(const float* __restrict__ ws,
                                                 const float* __restrict__ bn_gamma,
                                                 const float* __restrict__ bn_beta,
                                                 const float* __restrict__ w_ih,
                                                 const float* __restrict__ b_ih,
                                                 const float* __restrict__ w_hh,
                                                 const float* __restrict__ b_hh,
                                                 const float* __restrict__ w_out,
                                                 const float* __restrict__ b_out,
                                                 const float* __restrict__ ln_gamma,
                                                 const float* __restrict__ ln_beta,
                                                 float* __restrict__ out) {
    const int b = blockIdx.x;
    const int t = threadIdx.x;   // 256 threads; t == output index h

    __shared__ float scale_s[Cc], shift_s[Cc];
    __shared__ __align__(16) float pooled[Pc][Cc];
    __shared__ __align__(16) float u[Pc][HIDc];
    __shared__ __align__(16) float hx2[2][HIDc];
    __shared__ __align__(16) float o[OUTc];
    __shared__ float red2[2];

    // ---- Issue the full w_hh row fetch FIRST (256 KB/block in flight); it drains
    //      inside stage A's barrier, overlapping stage A's own scattered loads. ----
    float4 wreg[64];
    {
        const float4* wr = reinterpret_cast<const float4*>(w_hh) + t * (HIDc / 4);
#pragma unroll
        for (int e = 0; e < 64; ++e) wreg[e] = wr[e];
    }

    // ---- Stage A: channel stats (256-thread version; ws is L2/L3-hot) ----
    {
        const int c = t >> 3, r = t & 7;   // 8 threads per channel
        float s = 0.f, ss = 0.f;
#pragma unroll
        for (int j = 0; j < 16; ++j) {
            const int i = r + 8 * j;       // i in [0,128): i = b'*8 + p
            const int bid = ((i >> 3) * Cc + c) * Pc + (i & 7);
            s  += ws[2 * NBINS + bid];
            ss += ws[3 * NBINS + bid];
        }
#pragma unroll
        for (int off = 1; off < 8; off <<= 1) {
            s  += __shfl_xor(s, off);
            ss += __shfl_xor(ss, off);
        }
        if (r == 0) {
            const float mean = s * NPC_INV;
            const float var  = ss * NPC_INV - mean * mean;
            const float sc   = bn_gamma[c] * rsqrtf(var + EPS);
            scale_s[c] = sc;
            shift_s[c] = bn_beta[c] - mean * sc;
        }
    }
    __syncthreads();

    // ---- Stage B: pooled[p][c] = relu(scale * (scale>=0 ? max : min) + shift) ----
    {
        const int p = t >> 5, c = t & 31;  // 256 = 8p x 32c exactly
        const int bid = (b * Cc + c) * Pc + p;
        const float sc = scale_s[c];
        const float xm = (sc >= 0.f) ? ws[bid] : ws[NBINS + bid];
        pooled[p][c] = fmaxf(fmaf(sc, xm, shift_s[c]), 0.f);
    }
    __syncthreads();

    // ---- Stage C: u[p][t] for ALL p (thread t owns output t) ----
    {
        const float4* wi = reinterpret_cast<const float4*>(w_ih) + t * (Cc / 4);
        float4 wiv[8];
#pragma unroll
        for (int e = 0; e < 8; ++e) wiv[e] = wi[e];
        const float bias = b_ih[t] + b_hh[t];
#pragma unroll
        for (int p = 0; p < Pc; ++p) {
            const float4* pl = reinterpret_cast<const float4*>(&pooled[p][0]);
            float a0 = bias, a1 = 0.f, a2 = 0.f, a3 = 0.f;
#pragma unroll
            for (int e = 0; e < 8; ++e) {
                float4 pv = pl[e];
                a0 = fmaf(pv.x, wiv[e].x, a0);
                a1 = fmaf(pv.y, wiv[e].y, a1);
                a2 = fmaf(pv.z, wiv[e].z, a2);
                a3 = fmaf(pv.w, wiv[e].w, a3);
            }
            u[p][t] = (a0 + a1) + (a2 + a3);
        }
        // step 0: hx_prev = 0
        hx2[0][t] = fmaxf(u[0][t], 0.f);
    }
    __syncthreads();

    // ---- Stage D: 7 recurrent steps, ONE barrier each; hx double-buffered ----
    for (int step = 1; step < Pc; ++step) {
        const float4* hv4 = reinterpret_cast<const float4*>(&hx2[(step - 1) & 1][0]);
        float a0 = u[step][t], a1 = 0.f, a2 = 0.f, a3 = 0.f;
#pragma unroll
        for (int e = 0; e < 64; ++e) {
            float4 wv = wreg[e];
            float4 hv = hv4[e];
            a0 = fmaf(hv.x, wv.x, a0);
            a1 = fmaf(hv.y, wv.y, a1);
            a2 = fmaf(hv.z, wv.z, a2);
            a3 = fmaf(hv.w, wv.w, a3);
        }
        hx2[step & 1][t] = fmaxf((a0 + a1) + (a2 + a3), 0.f);
        __syncthreads();
    }
    // final hx is hx2[(Pc-1)&1] = hx2[1]

    // ---- Stage E: out = hx @ w_out^T + b_out ----
    if (t < OUTc) {
        const float4* wo = reinterpret_cast<const float4*>(w_out) + t * (HIDc / 4);
        const float4* hv4 = reinterpret_cast<const float4*>(&hx2[1][0]);
        float a0 = b_out[t], a1 = 0.f, a2 = 0.f, a3 = 0.f;
#pragma unroll
        for (int e = 0; e < 64; ++e) {
            float4 wv = wo[e];
            float4 hv = hv4[e];
            a0 = fmaf(hv.x, wv.x, a0);
            a1 = fmaf(hv.y, wv.y, a1);
            a2 = fmaf(hv.z, wv.z, a2);
            a3 = fmaf(hv.w, wv.w, a3);
        }
        o[t] = (a0 + a1) + (a2 + a3);
    }
    __syncthreads();

    // ---- LayerNorm over 128 ----
    if (t < 64) {
        const float x0 = o[t], x1 = o[t + 64];
        float s = x0 + x1, ss = x0 * x0 + x1 * x1;
#pragma unroll
        for (int off = 1; off < 64; off <<= 1) {
            s  += __shfl_xor(s, off);
            ss += __shfl_xor(ss, off);
        }
        if (t == 0) { red2[0] = s; red2[1] = ss; }
    }
    __syncthreads();
    if (t < OUTc) {
        const float mu  = red2[0] * (1.0f / OUTc);
        const float var = red2[1] * (1.0f / OUTc) - mu * mu;
        const float rs  = rsqrtf(var + EPS);
        out[b * OUTc + t] = (o[t] - mu) * rs * ln_gamma[t] + ln_beta[t];
    }
}

extern "C" void kernel_launch(void* const* d_in, const int* in_sizes, int n_in,
                              void* d_out, int out_size, void* d_ws, size_t ws_size,
                              hipStream_t stream) {
    const float* x        = (const float*)d_in[0];
    const float* bn_gamma = (const float*)d_in[1];
    const float* bn_beta  = (const float*)d_in[2];
    const float* w_ih     = (const float*)d_in[3];
    const float* b_ih     = (const float*)d_in[4];
    const float* w_hh     = (const float*)d_in[5];
    const float* b_hh     = (const float*)d_in[6];
    const float* w_out    = (const float*)d_in[7];
    const float* b_out    = (const float*)d_in[8];
    const float* ln_gamma = (const float*)d_in[9];
    const float* ln_beta  = (const float*)d_in[10];
    float* out = (float*)d_out;
    float* ws  = (float*)d_ws;

    k1_stats<<<NBINS, 256, 0, stream>>>(x, ws);
    k2_rnn<<<Bc, 256, 0, stream>>>(ws, bn_gamma, bn_beta, w_ih, b_ih, w_hh, b_hh,
                                   w_out, b_out, ln_gamma, ln_beta, out);
}

// Round 8
// 64.619 us; speedup vs baseline: 1.6857x; 1.0895x over previous
//
#include <hip/hip_runtime.h>
#include <math.h>

#define EPS 1e-5f

constexpr int Bc = 16, Cc = 32, Pc = 8, HIDc = 256, OUTc = 128;
constexpr int NBINS = 4096;
constexpr float NPC_INV = 1.0f / 2097152.0f;

typedef float fx4 __attribute__((ext_vector_type(4)));

// ws layout (floats): [0,4096) max | [4096,8192) min | [8192,12288) sum | [12288,16384) sumsq

// ---------------- Kernel 1: unchanged (41 us = 6.5 TB/s, at read ceiling per r6) ----------------
__global__ __launch_bounds__(256) void k1_stats(const float* __restrict__ x,
                                                float* __restrict__ ws) {
    const int bid = blockIdx.x;
    const int t = threadIdx.x;
    const fx4* px = reinterpret_cast<const fx4*>(x) + ((size_t)bid << 12);

    float vmax = -INFINITY, vmin = INFINITY, s = 0.f, ss = 0.f;
#pragma unroll
    for (int j = 0; j < 16; ++j) {
        fx4 v = __builtin_nontemporal_load(&px[j * 256 + t]);
        vmax = fmaxf(vmax, fmaxf(fmaxf(v.x, v.y), fmaxf(v.z, v.w)));
        vmin = fminf(vmin, fminf(fminf(v.x, v.y), fminf(v.z, v.w)));
        s += (v.x + v.y) + (v.z + v.w);
        ss = fmaf(v.x, v.x, ss); ss = fmaf(v.y, v.y, ss);
        ss = fmaf(v.z, v.z, ss); ss = fmaf(v.w, v.w, ss);
    }
#pragma unroll
    for (int off = 1; off < 64; off <<= 1) {
        vmax = fmaxf(vmax, __shfl_xor(vmax, off));
        vmin = fminf(vmin, __shfl_xor(vmin, off));
        s += __shfl_xor(s, off);
        ss += __shfl_xor(ss, off);
    }
    __shared__ float r[4][4];
    const int wid = t >> 6;
    if ((t & 63) == 0) { r[wid][0] = vmax; r[wid][1] = vmin; r[wid][2] = s; r[wid][3] = ss; }
    __syncthreads();
    if (t == 0) {
        vmax = fmaxf(fmaxf(r[0][0], r[1][0]), fmaxf(r[2][0], r[3][0]));
        vmin = fminf(fminf(r[0][1], r[1][1]), fminf(r[2][1], r[3][1]));
        s  = (r[0][2] + r[1][2]) + (r[2][2] + r[3][2]);
        ss = (r[0][3] + r[1][3]) + (r[2][3] + r[3][3]);
        ws[bid]             = vmax;
        ws[NBINS + bid]     = vmin;
        ws[2 * NBINS + bid] = s;
        ws[3 * NBINS + bid] = ss;
    }
}

// ---------------- Kernel 2: 16 blocks x 512 threads, tiled register reuse ----------------
// Thread t: og = t>>3 (4 outputs 4og..4og+3), kg = t&7 (k-slice [32kg, 32kg+32)).
// w-tile 4x32 = 32 float4 in VGPRs -> 1 FMA per LDS byte (4x reuse vs r7).
// hx in LDS swizzled: word(k) = (k>>5)*36 + (k&31)  -> conflict-free b128 reads.
__global__ __launch_bounds__(512, 2) void k2_rnn(const float* __restrict__ ws,
                                                 const float* __restrict__ bn_gamma,
                                                 const float* __restrict__ bn_beta,
                                                 const float* __restrict__ w_ih,
                                                 const float* __restrict__ b_ih,
                                                 const float* __restrict__ w_hh,
                                                 const float* __restrict__ b_hh,
                                                 const float* __restrict__ w_out,
                                                 const float* __restrict__ b_out,
                                                 const float* __restrict__ ln_gamma,
                                                 const float* __restrict__ ln_beta,
                                                 float* __restrict__ out) {
    const int b = blockIdx.x;
    const int t = threadIdx.x;                 // 512 threads
    const int og = t >> 3, kg = t & 7;

    __shared__ float scale_s[Cc], shift_s[Cc];
    __shared__ float pA[2][Cc], pB[2][Cc];
    __shared__ __align__(16) float pooled[Pc][Cc];
    __shared__ __align__(16) float u[Pc][HIDc];
    __shared__ __align__(16) float hxs[2][288];   // 8 groups * 36 words, double-buffered
    __shared__ __align__(16) float o[OUTc];
    __shared__ float red2[2];

    // ---- Stage A: channel stats, fully coalesced (c is constant per thread) ----
    {
        const float* sums = ws + 2 * NBINS;
        const float* sqs  = ws + 3 * NBINS;
        float s = 0.f, ss = 0.f;
#pragma unroll
        for (int j = 0; j < 8; ++j) {          // flat = t + 512j: c=(t>>3)&31 invariant
            s  += sums[t + 512 * j];
            ss += sqs[t + 512 * j];
        }
#pragma unroll
        for (int off = 1; off < 8; off <<= 1) {
            s  += __shfl_xor(s, off);
            ss += __shfl_xor(ss, off);
        }
        if ((t & 7) == 0) {
            const int c = (t >> 3) & 31, half = t >> 8;
            pA[half][c] = s;
            pB[half][c] = ss;
        }
    }

    // ---- Issue w_hh tile loads (256 KB/block); stages A-tail/B/C cover part ----
    float4 w4[4][8];
#pragma unroll
    for (int r = 0; r < 4; ++r) {
        const float4* wr = reinterpret_cast<const float4*>(w_hh + (4 * og + r) * HIDc + 32 * kg);
#pragma unroll
        for (int e = 0; e < 8; ++e) w4[r][e] = wr[e];
    }

    __syncthreads();
    if (t < Cc) {
        const float s = pA[0][t] + pA[1][t], ss = pB[0][t] + pB[1][t];
        const float mean = s * NPC_INV;
        const float var  = ss * NPC_INV - mean * mean;
        const float sc   = bn_gamma[t] * rsqrtf(var + EPS);
        scale_s[t] = sc;
        shift_s[t] = bn_beta[t] - mean * sc;
    }
    __syncthreads();

    // ---- Stage B: pooled (coalesced: bid = b*256 + t) ----
    if (t < Pc * Cc) {
        const int c = t >> 3, p = t & 7;
        const int bid = b * 256 + t;
        const float sc = scale_s[c];
        const float xm = (sc >= 0.f) ? ws[bid] : ws[NBINS + bid];
        pooled[p][c] = fmaxf(fmaf(sc, xm, shift_s[c]), 0.f);
    }
    __syncthreads();

    // ---- Stage C: u[p][h], 512 threads = 256 h x 2 p-halves (4 p each) ----
    {
        const int h = t & 255, pq = t >> 8;
        const float4* wi = reinterpret_cast<const float4*>(w_ih) + h * (Cc / 4);
        float4 wiv[8];
#pragma unroll
        for (int e = 0; e < 8; ++e) wiv[e] = wi[e];
        const float bias = b_ih[h] + b_hh[h];
        float u0 = 0.f;
#pragma unroll
        for (int pp = 0; pp < 4; ++pp) {
            const int p = pq * 4 + pp;
            const float4* pl = reinterpret_cast<const float4*>(&pooled[p][0]);
            float a0 = bias, a1 = 0.f, a2 = 0.f, a3 = 0.f;
#pragma unroll
            for (int e = 0; e < 8; ++e) {
                float4 pv = pl[e];
                a0 = fmaf(pv.x, wiv[e].x, a0);
                a1 = fmaf(pv.y, wiv[e].y, a1);
                a2 = fmaf(pv.z, wiv[e].z, a2);
                a3 = fmaf(pv.w, wiv[e].w, a3);
            }
            const float uv = (a0 + a1) + (a2 + a3);
            u[p][h] = uv;
            if (pp == 0) u0 = uv;
        }
        // step 0: hx = relu(u[0]); u0 is this thread's own value when pq==0
        if (pq == 0) hxs[0][(h >> 5) * 36 + (h & 31)] = fmaxf(u0, 0.f);
    }
    __syncthreads();   // drains w_hh loads too

    // ---- Stage D: 7 recurrent steps, one barrier each ----
    int cur = 0;
    for (int step = 1; step < Pc; ++step) {
        float4 h4[8];
        const float4* hp = reinterpret_cast<const float4*>(&hxs[cur][kg * 36]);
#pragma unroll
        for (int e = 0; e < 8; ++e) h4[e] = hp[e];
        float acc[4];
#pragma unroll
        for (int r = 0; r < 4; ++r) {
            float a0 = 0.f, a1 = 0.f, a2 = 0.f, a3 = 0.f;
#pragma unroll
            for (int e = 0; e < 8; ++e) {
                float4 wv = w4[r][e], hv = h4[e];
                a0 = fmaf(hv.x, wv.x, a0);
                a1 = fmaf(hv.y, wv.y, a1);
                a2 = fmaf(hv.z, wv.z, a2);
                a3 = fmaf(hv.w, wv.w, a3);
            }
            acc[r] = (a0 + a1) + (a2 + a3);
        }
#pragma unroll
        for (int off = 1; off < 8; off <<= 1) {
#pragma unroll
            for (int r = 0; r < 4; ++r) acc[r] += __shfl_xor(acc[r], off);
        }
        if (kg == 0) {
#pragma unroll
            for (int r = 0; r < 4; ++r) {
                const int h = 4 * og + r;
                const float v = u[step][h] + acc[r];
                hxs[cur ^ 1][(h >> 5) * 36 + (h & 31)] = fmaxf(v, 0.f);
            }
        }
        __syncthreads();
        cur ^= 1;
    }
    // final hx in hxs[1]

    // ---- Stage E: out = hx @ w_out^T + b_out (4 threads/output, 64-k slices) ----
    {
        const int oi = t >> 2, seg = t & 3;
        const float4* wo = reinterpret_cast<const float4*>(w_out + oi * HIDc + seg * 64);
        float a0 = (seg == 0) ? b_out[oi] : 0.f, a1 = 0.f, a2 = 0.f, a3 = 0.f;
#pragma unroll
        for (int e = 0; e < 16; ++e) {
            const int k = seg * 64 + e * 4;
            const float4 hv = *reinterpret_cast<const float4*>(&hxs[1][(k >> 5) * 36 + (k & 31)]);
            const float4 wv = wo[e];
            a0 = fmaf(hv.x, wv.x, a0);
            a1 = fmaf(hv.y, wv.y, a1);
            a2 = fmaf(hv.z, wv.z, a2);
            a3 = fmaf(hv.w, wv.w, a3);
        }
        float s = (a0 + a1) + (a2 + a3);
        s += __shfl_xor(s, 1);
        s += __shfl_xor(s, 2);
        if (seg == 0) o[oi] = s;
    }
    __syncthreads();

    // ---- LayerNorm over 128 ----
    if (t < 64) {
        const float x0 = o[t], x1 = o[t + 64];
        float s = x0 + x1, ss = x0 * x0 + x1 * x1;
#pragma unroll
        for (int off = 1; off < 64; off <<= 1) {
            s  += __shfl_xor(s, off);
            ss += __shfl_xor(ss, off);
        }
        if (t == 0) { red2[0] = s; red2[1] = ss; }
    }
    __syncthreads();
    if (t < OUTc) {
        const float mu  = red2[0] * (1.0f / OUTc);
        const float var = red2[1] * (1.0f / OUTc) - mu * mu;
        const float rs  = rsqrtf(var + EPS);
        out[b * OUTc + t] = (o[t] - mu) * rs * ln_gamma[t] + ln_beta[t];
    }
}

extern "C" void kernel_launch(void* const* d_in, const int* in_sizes, int n_in,
                              void* d_out, int out_size, void* d_ws, size_t ws_size,
                              hipStream_t stream) {
    const float* x        = (const float*)d_in[0];
    const float* bn_gamma = (const float*)d_in[1];
    const float* bn_beta  = (const float*)d_in[2];
    const float* w_ih     = (const float*)d_in[3];
    const float* b_ih     = (const float*)d_in[4];
    const float* w_hh     = (const float*)d_in[5];
    const float* b_hh     = (const float*)d_in[6];
    const float* w_out    = (const float*)d_in[7];
    const float* b_out    = (const float*)d_in[8];
    const float* ln_gamma = (const float*)d_in[9];
    const float* ln_beta  = (const float*)d_in[10];
    float* out = (float*)d_out;
    float* ws  = (float*)d_ws;

    k1_stats<<<NBINS, 256, 0, stream>>>(x, ws);
    k2_rnn<<<Bc, 512, 0, stream>>>(ws, bn_gamma, bn_beta, w_ih, b_ih, w_hh, b_hh,
                                   w_out, b_out, ln_gamma, ln_beta, out);
}